// Round 6
// baseline (175.083 us; speedup 1.0000x reference)
//
#include <hip/hip_runtime.h>
#include <hip/hip_bf16.h>

typedef __attribute__((ext_vector_type(8))) short bf16x8;
typedef __attribute__((ext_vector_type(4))) float f32x4;
typedef __attribute__((ext_vector_type(4))) int i32x4;

// RNE round two fp32 -> packed bf16 pair (elem a = low half)
__device__ inline unsigned int pack_bf2(float a, float b) {
    unsigned int ua = __builtin_bit_cast(unsigned int, a);
    unsigned int ub = __builtin_bit_cast(unsigned int, b);
    ua = (ua + 0x7fffu + ((ua >> 16) & 1u)) >> 16;
    ub = (ub + 0x7fffu + ((ub >> 16) & 1u)) >> 16;
    return (ub << 16) | (ua & 0xffffu);
}

// ---------------------------------------------------------------------------
// Kernel 1: repack conv_w [K=768][N=256] fp32 -> bf16 in MFMA B-fragment order.
// Bpack frag index t = (nt*24 + ksg)*64 + lane, 8 bf16 per t (one int4).
// Fragment semantics: B[k][n], k = ksg*32 + (lane>>4)*8 + j, n = nt*16 + (lane&15).
// ---------------------------------------------------------------------------
__global__ void pack_w_kernel(const float* __restrict__ conv_w, i32x4* __restrict__ bpack) {
    int t = blockIdx.x * 256 + threadIdx.x;       // 0 .. 24575
    int lane = t & 63;
    int g = t >> 6;                                // nt*24 + ksg
    int nt = g / 24, ks = g - nt * 24;
    int k0 = ks * 32 + ((lane >> 4) << 3);
    int n  = nt * 16 + (lane & 15);
    const float* src = conv_w + (size_t)k0 * 256 + n;
    float v[8];
#pragma unroll
    for (int j = 0; j < 8; ++j) v[j] = src[(size_t)j * 256];
    i32x4 o;
    o.x = pack_bf2(v[0], v[1]);
    o.y = pack_bf2(v[2], v[3]);
    o.z = pack_bf2(v[4], v[5]);
    o.w = pack_bf2(v[6], v[7]);
    bpack[t] = o;
}

// ---------------------------------------------------------------------------
// Kernel 2 (R6): conv stem as bf16 MFMA patch-GEMM, K-chunk=384 (2 chunks),
// single 49 KB LDS buffer, 4 barriers/pass. Chunk-1 global loads issued at
// the TOP of chunk-0 compute -> ~2500cyc of cover before the barrier drain
// (the m97 vmcnt(0)-before-s_barrier drain made 8-chunk pipelines stall).
// Block 512 thr = 8 waves (2M x 4N), tile M=64 x N=128, wave 32x32.
// B streamed from L2 via explicit 2-ahead ring (6 i32x4).
// INTERNAL 3x REP LOOP (idempotent): one long dispatch so rocprof top-5
// finally shows conv's counters; timed total = other + 3*conv.
// ---------------------------------------------------------------------------
__global__ __launch_bounds__(512, 4) void conv_kernel(
    const float* __restrict__ images,
    const i32x4* __restrict__ bpack,
    const float* __restrict__ conv_b,
    float* __restrict__ feat) {
    __shared__ short ldsA[64 * 392];   // 64 patches x 384 k (+8 pad) = 49 KB

    const int tid  = threadIdx.x;
    const int lane = tid & 63;
    const int w    = tid >> 6;        // wave 0..7
    const int l15  = lane & 15;
    const int lg   = lane >> 4;       // 0..3
    const int wr   = w >> 2;          // wave M-half 0..1
    const int wc   = w & 3;           // wave N-quarter 0..3

    // XCD swizzle: consecutive works (nhalf pair of same strips) share an XCD
    const int work  = (blockIdx.x & 7) * 64 + (blockIdx.x >> 3);
    const int mi    = work >> 1;      // strip pair (M-block of 64)
    const int nhalf = work & 1;

    // staging map: strip ss (0..1), row-group r4 (0..3; rows r4 & r4+4), tc (0..63)
    const int ss = tid >> 8;
    const int r4 = (tid >> 6) & 3;
    const int tc = tid & 63;
    const int gstrip = 2 * mi + ss;
    const float* tbase = images
        + (size_t)(((gstrip >> 5) << 9) + ((gstrip & 31) << 4)) * 1536 + tc * 4;

    // LDS write base indices per float4 slot p (row term added at use)
    int widx[6];
#pragma unroll
    for (int p = 0; p < 6; ++p) {
        int f0 = tc * 4 + p * 256;        // float index within image row
        int j = f0 / 48;                  // patch column 0..31
        int off = f0 - 48 * j;
        widx[p] = (ss * 32 + j) * 392 + off;
    }

    float bias[2];
#pragma unroll
    for (int sub = 0; sub < 2; ++sub)
        bias[sub] = conv_b[nhalf * 128 + wc * 32 + sub * 16 + l15];

    // B fragments: nt = nhalf*8 + wc*2 + sub, index (sub*24 + ksg)*64
    const i32x4* bp = bpack + (size_t)((nhalf * 8 + wc * 2) * 24) * 64 + lane;
    const short* arow0 = &ldsA[(wr * 32 + l15) * 392];
    const short* arow1 = &ldsA[(wr * 32 + 16 + l15) * 392];

    for (int rep = 0; rep < 3; ++rep) {
        __syncthreads();                  // previous rep's readers done
        f32x4 acc[2][2] = {};

        // ---- stage chunk 0 (rows 0..7 of each strip) ----
        {
            f32x4 ld[2][6];
#pragma unroll
            for (int r2 = 0; r2 < 2; ++r2)
#pragma unroll
            for (int p = 0; p < 6; ++p)
                ld[r2][p] = *(const f32x4*)(tbase + (size_t)(r4 + 4 * r2) * 1536 + p * 256);
#pragma unroll
            for (int r2 = 0; r2 < 2; ++r2)
#pragma unroll
            for (int p = 0; p < 6; ++p) {
                int2 v;
                v.x = pack_bf2(ld[r2][p].x, ld[r2][p].y);
                v.y = pack_bf2(ld[r2][p].z, ld[r2][p].w);
                *(int2*)(&ldsA[widx[p] + (r4 + 4 * r2) * 48]) = v;
            }
        }
        __syncthreads();

        // issue chunk-1 loads NOW: entire chunk-0 compute hides their latency
        f32x4 st[2][6];
#pragma unroll
        for (int r2 = 0; r2 < 2; ++r2)
#pragma unroll
        for (int p = 0; p < 6; ++p)
            st[r2][p] = *(const f32x4*)(tbase + (size_t)(8 + r4 + 4 * r2) * 1536 + p * 256);

        // ---- compute chunk 0 (ksg 0..11) ----
        {
            i32x4 Br[3][2];
#pragma unroll
            for (int sub = 0; sub < 2; ++sub) {
                Br[0][sub] = bp[(size_t)(sub * 24 + 0) * 64];
                Br[1][sub] = bp[(size_t)(sub * 24 + 1) * 64];
            }
#pragma unroll
            for (int s = 0; s < 12; ++s) {
                if (s < 10) {
#pragma unroll
                    for (int sub = 0; sub < 2; ++sub)
                        Br[(s + 2) % 3][sub] = bp[(size_t)(sub * 24 + s + 2) * 64];
                }
                bf16x8 aF0 = *(const bf16x8*)(&arow0[s * 32 + lg * 8]);
                bf16x8 aF1 = *(const bf16x8*)(&arow1[s * 32 + lg * 8]);
#pragma unroll
                for (int sub = 0; sub < 2; ++sub) {
                    bf16x8 bF = __builtin_bit_cast(bf16x8, Br[s % 3][sub]);
                    acc[0][sub] = __builtin_amdgcn_mfma_f32_16x16x32_bf16(aF0, bF, acc[0][sub], 0, 0, 0);
                    acc[1][sub] = __builtin_amdgcn_mfma_f32_16x16x32_bf16(aF1, bF, acc[1][sub], 0, 0, 0);
                }
            }
        }
        __syncthreads();                  // all waves done reading chunk 0

        // ---- write chunk 1 (loads landed long ago) ----
#pragma unroll
        for (int r2 = 0; r2 < 2; ++r2)
#pragma unroll
        for (int p = 0; p < 6; ++p) {
            int2 v;
            v.x = pack_bf2(st[r2][p].x, st[r2][p].y);
            v.y = pack_bf2(st[r2][p].z, st[r2][p].w);
            *(int2*)(&ldsA[widx[p] + (r4 + 4 * r2) * 48]) = v;
        }
        __syncthreads();

        // ---- compute chunk 1 (ksg 12..23) ----
        {
            i32x4 Br[3][2];
#pragma unroll
            for (int sub = 0; sub < 2; ++sub) {
                Br[0][sub] = bp[(size_t)(sub * 24 + 12) * 64];
                Br[1][sub] = bp[(size_t)(sub * 24 + 13) * 64];
            }
#pragma unroll
            for (int s = 0; s < 12; ++s) {
                if (s < 10) {
#pragma unroll
                    for (int sub = 0; sub < 2; ++sub)
                        Br[(s + 2) % 3][sub] = bp[(size_t)(sub * 24 + 12 + s + 2) * 64];
                }
                bf16x8 aF0 = *(const bf16x8*)(&arow0[s * 32 + lg * 8]);
                bf16x8 aF1 = *(const bf16x8*)(&arow1[s * 32 + lg * 8]);
#pragma unroll
                for (int sub = 0; sub < 2; ++sub) {
                    bf16x8 bF = __builtin_bit_cast(bf16x8, Br[s % 3][sub]);
                    acc[0][sub] = __builtin_amdgcn_mfma_f32_16x16x32_bf16(aF0, bF, acc[0][sub], 0, 0, 0);
                    acc[1][sub] = __builtin_amdgcn_mfma_f32_16x16x32_bf16(aF1, bF, acc[1][sub], 0, 0, 0);
                }
            }
        }

        // epilogue: D row in 16-tile = 4*lg + r, col = l15
        const int m0 = mi * 64 + wr * 32;
        const int nc0 = nhalf * 128 + wc * 32;
#pragma unroll
        for (int mt = 0; mt < 2; ++mt)
#pragma unroll
        for (int sub = 0; sub < 2; ++sub)
#pragma unroll
        for (int r = 0; r < 4; ++r) {
            int m = m0 + mt * 16 + lg * 4 + r;
            float v = acc[mt][sub][r] + bias[sub];
            feat[(size_t)m * 256 + nc0 + sub * 16 + l15] = fmaxf(v, 0.f);
        }
    }
}

// ---------------------------------------------------------------------------
// Kernel 3: RoI-align (7x7 bilinear, mean) + mask + dense.  1 block per (b,n).
// FROZEN (decomposition baseline).
// ---------------------------------------------------------------------------
__global__ __launch_bounds__(512) void roi_dense_kernel(
    const float* __restrict__ bboxes,
    const float* __restrict__ feat,
    const float* __restrict__ dense_w,
    const float* __restrict__ dense_b,
    float* __restrict__ out) {
    __shared__ int   offs[4][49];
    __shared__ float wts[4][49];
    __shared__ float part[512];
    __shared__ float objv[256];

    const int bn = blockIdx.x;         // b*16 + n
    const int b  = bn >> 4;
    const int tid = threadIdx.x;

    const float4 box = *(const float4*)(bboxes + (size_t)bn * 4); // ymin,xmin,ymax,xmax
    bool empty = (box.x == -1.f) & (box.y == -1.f) & (box.z == -1.f) & (box.w == -1.f);
    if (empty) {
        if (tid < 256) out[(size_t)bn * 256 + tid] = dense_b[tid];
        return;
    }

    if (tid < 49) {
        int sy = tid / 7, sx = tid - sy * 7;
        float py = (box.x + (box.z - box.x) * ((sy + 0.5f) * (1.0f / 7.0f))) * 32.f - 0.5f;
        float px = (box.y + (box.w - box.y) * ((sx + 0.5f) * (1.0f / 7.0f))) * 32.f - 0.5f;
        float y0f = floorf(py), x0f = floorf(px);
        float wy = py - y0f, wx = px - x0f;
        int y0 = min(max((int)y0f, 0), 31);
        int y1 = min(max((int)y0f + 1, 0), 31);
        int x0 = min(max((int)x0f, 0), 31);
        int x1 = min(max((int)x0f + 1, 0), 31);
        offs[0][tid] = (y0 * 32 + x0) * 256;
        offs[1][tid] = (y0 * 32 + x1) * 256;
        offs[2][tid] = (y1 * 32 + x0) * 256;
        offs[3][tid] = (y1 * 32 + x1) * 256;
        wts[0][tid] = (1.f - wy) * (1.f - wx);
        wts[1][tid] = (1.f - wy) * wx;
        wts[2][tid] = wy * (1.f - wx);
        wts[3][tid] = wy * wx;
    }
    __syncthreads();

    const int c = tid & 255, h = tid >> 8;
    const float* fb = feat + (size_t)b * (1024 * 256) + c;
    float accv = 0.f;
    for (int s = h; s < 49; s += 2) {
        accv += wts[0][s] * fb[offs[0][s]];
        accv += wts[1][s] * fb[offs[1][s]];
        accv += wts[2][s] * fb[offs[2][s]];
        accv += wts[3][s] * fb[offs[3][s]];
    }
    part[tid] = accv;
    __syncthreads();
    if (tid < 256) objv[tid] = (part[tid] + part[tid + 256]) * (1.f / 49.f);
    __syncthreads();

    const float* dwp = dense_w + (size_t)(h * 128) * 256 + c;
    float da = 0.f;
#pragma unroll 8
    for (int cc = 0; cc < 128; ++cc) da += objv[h * 128 + cc] * dwp[(size_t)cc * 256];
    part[tid] = da;
    __syncthreads();
    if (tid < 256) out[(size_t)bn * 256 + tid] = part[tid] + part[tid + 256] + dense_b[tid];
}

extern "C" void kernel_launch(void* const* d_in, const int* in_sizes, int n_in,
                              void* d_out, int out_size, void* d_ws, size_t ws_size,
                              hipStream_t stream) {
    const float* images  = (const float*)d_in[0];   // [16,512,512,3]
    const float* bboxes  = (const float*)d_in[1];   // [16,16,4]
    const float* conv_w  = (const float*)d_in[2];   // [16,16,3,256]
    const float* conv_b  = (const float*)d_in[3];   // [256]
    const float* dense_w = (const float*)d_in[4];   // [256,256]
    const float* dense_b = (const float*)d_in[5];   // [256]
    float* out = (float*)d_out;

    char* ws = (char*)d_ws;
    i32x4* bpack = (i32x4*)ws;                      // 384 KiB (bf16 B fragments)
    float* feat  = (float*)(ws + 512 * 1024);       // 16384*256 fp32 = 16 MiB

    pack_w_kernel<<<96, 256, 0, stream>>>(conv_w, bpack);
    // conv loops 3x internally (idempotent): one long dispatch -> counters
    // finally visible in top-5; timed total = other + 3*conv.
    conv_kernel<<<512, 512, 0, stream>>>(images, bpack, conv_b, feat);
    roi_dense_kernel<<<256, 512, 0, stream>>>(bboxes, feat, dense_w, dense_b, out);
}

// Round 7
// 40.430 us; speedup vs baseline: 4.3306x; 4.3306x over previous
//
#include <hip/hip_runtime.h>
#include <hip/hip_bf16.h>

typedef __attribute__((ext_vector_type(8))) short bf16x8;
typedef __attribute__((ext_vector_type(4))) float f32x4;
typedef __attribute__((ext_vector_type(4))) int i32x4;

// RNE round two fp32 -> packed bf16 pair (elem a = low half)
__device__ inline unsigned int pack_bf2(float a, float b) {
    unsigned int ua = __builtin_bit_cast(unsigned int, a);
    unsigned int ub = __builtin_bit_cast(unsigned int, b);
    ua = (ua + 0x7fffu + ((ua >> 16) & 1u)) >> 16;
    ub = (ub + 0x7fffu + ((ub >> 16) & 1u)) >> 16;
    return (ub << 16) | (ua & 0xffffu);
}

// ---------------------------------------------------------------------------
// Kernel 1: repack conv_w [K=768][N=256] fp32 -> bf16 in MFMA B-fragment order.
// Bpack frag index t = (nt*24 + ksg)*64 + lane, 8 bf16 per t (one int4).
// Fragment semantics: B[k][n], k = ksg*32 + (lane>>4)*8 + j, n = nt*16 + (lane&15).
// ---------------------------------------------------------------------------
__global__ void pack_w_kernel(const float* __restrict__ conv_w, i32x4* __restrict__ bpack) {
    int t = blockIdx.x * 256 + threadIdx.x;       // 0 .. 24575
    int lane = t & 63;
    int g = t >> 6;                                // nt*24 + ksg
    int nt = g / 24, ks = g - nt * 24;
    int k0 = ks * 32 + ((lane >> 4) << 3);
    int n  = nt * 16 + (lane & 15);
    const float* src = conv_w + (size_t)k0 * 256 + n;
    float v[8];
#pragma unroll
    for (int j = 0; j < 8; ++j) v[j] = src[(size_t)j * 256];
    i32x4 o;
    o.x = pack_bf2(v[0], v[1]);
    o.y = pack_bf2(v[2], v[3]);
    o.z = pack_bf2(v[4], v[5]);
    o.w = pack_bf2(v[6], v[7]);
    bpack[t] = o;
}

// ---------------------------------------------------------------------------
// Kernel 2 (R7): R5 structure, SPILL FIX.
// R6 counters proved __launch_bounds__(512,4) compiles as CUDA-style
// "min 4 blocks/CU" -> 32 waves/CU -> 64 VGPRs -> ~100-reg working set
// spilled to scratch (WRITE_SIZE 237MB vs 48MB ideal). No min-arg here:
// compiler free to allocate ~100-130 VGPRs; LDS 26.6KB still allows
// multiple blocks/CU.
// Block: 512 thr = 8 waves (2M x 4N). Tile M=64 x N=128; wave M=32 x N=32.
// K-chunk=96 staged to LDS bf16 (stride 104), double-buffered. Grid 512.
// B loaded per-chunk from L2 (issued right after barrier, before image
// prefetch, so the MFMA vmcnt wait doesn't drain the image loads).
// ---------------------------------------------------------------------------
__global__ __launch_bounds__(512) void conv_kernel(
    const float* __restrict__ images,
    const i32x4* __restrict__ bpack,
    const float* __restrict__ conv_b,
    float* __restrict__ feat) {
    __shared__ short ldsA[2][64 * 104];   // [buf][patch 0..63][k 0..95, stride 104]

    const int tid  = threadIdx.x;
    const int lane = tid & 63;
    const int w    = tid >> 6;        // wave 0..7
    const int l15  = lane & 15;
    const int lg   = lane >> 4;       // 0..3
    const int wr   = w >> 2;          // wave M-row 0..1
    const int wc   = w & 3;           // wave N-col 0..3

    // XCD swizzle: consecutive works (nhalf pair of same strips) share an XCD
    const int work  = (blockIdx.x & 7) * 64 + (blockIdx.x >> 3);
    const int mi    = work >> 1;      // strip pair index (M-block of 64)
    const int nhalf = work & 1;

    // staging coords: strip ss (0..1), row-in-chunk sr (0..1), col tc (0..127)
    const int ss = tid >> 8;
    const int sr = (tid >> 7) & 1;
    const int tc = tid & 127;
    const int gstrip = 2 * mi + ss;
    const float* rowbase = images
        + (size_t)(((gstrip >> 5) << 9) + ((gstrip & 31) << 4) + sr) * 1536 + tc * 4;

    // staging LDS indices (3 writes/thread), precomputed
    int widx[3];
#pragma unroll
    for (int p = 0; p < 3; ++p) {
        int fp = tc + (p << 7);               // float4 index in row [0,384)
        int j = (fp * 1366) >> 14;            // fp/12 exact for fp<384
        int q = fp - 12 * j;
        widx[p] = (ss * 32 + j) * 104 + sr * 48 + (q << 2);
    }

    float bias[2];
#pragma unroll
    for (int sub = 0; sub < 2; ++sub)
        bias[sub] = conv_b[nhalf * 128 + wc * 32 + sub * 16 + l15];

    // B fragment base: nt = nhalf*8 + wc*2 + sub, frag offset (sub*24 + ksg)*64
    const i32x4* bp = bpack + (size_t)((nhalf * 8 + wc * 2) * 24) * 64 + lane;

    f32x4 acc[2][2] = {};
    f32x4 st[3];

    // ---- prologue: stage chunk 0 ----
#pragma unroll
    for (int p = 0; p < 3; ++p) st[p] = *(const f32x4*)(rowbase + p * 512);
#pragma unroll
    for (int p = 0; p < 3; ++p) {
        int2 v;
        v.x = pack_bf2(st[p].x, st[p].y);
        v.y = pack_bf2(st[p].z, st[p].w);
        *(int2*)(&ldsA[0][widx[p]]) = v;
    }
    __syncthreads();

#pragma unroll
    for (int c = 0; c < 8; ++c) {
        // B for THIS chunk: issued first so the MFMA wait leaves image loads in flight
        i32x4 Bc[2][3];
#pragma unroll
        for (int sub = 0; sub < 2; ++sub)
#pragma unroll
        for (int s = 0; s < 3; ++s)
            Bc[sub][s] = bp[(size_t)(sub * 24 + c * 3 + s) * 64];
        // image prefetch for chunk c+1 (consumed after the compute phase)
        if (c < 7) {
            const float* rb = rowbase + (size_t)(c + 1) * 3072;
#pragma unroll
            for (int p = 0; p < 3; ++p) st[p] = *(const f32x4*)(rb + p * 512);
        }
        // compute chunk c from LDS buf (c&1)
        const short* bufA = &ldsA[c & 1][0];
#pragma unroll
        for (int s = 0; s < 3; ++s) {
            bf16x8 aF0 = *(const bf16x8*)(&bufA[(wr * 32 + l15) * 104 + s * 32 + lg * 8]);
            bf16x8 aF1 = *(const bf16x8*)(&bufA[(wr * 32 + 16 + l15) * 104 + s * 32 + lg * 8]);
#pragma unroll
            for (int sub = 0; sub < 2; ++sub) {
                bf16x8 bF = __builtin_bit_cast(bf16x8, Bc[sub][s]);
                acc[0][sub] = __builtin_amdgcn_mfma_f32_16x16x32_bf16(aF0, bF, acc[0][sub], 0, 0, 0);
                acc[1][sub] = __builtin_amdgcn_mfma_f32_16x16x32_bf16(aF1, bF, acc[1][sub], 0, 0, 0);
            }
        }
        // stage chunk c+1 into other buffer
        if (c < 7) {
            short* dstA = &ldsA[(c + 1) & 1][0];
#pragma unroll
            for (int p = 0; p < 3; ++p) {
                int2 v;
                v.x = pack_bf2(st[p].x, st[p].y);
                v.y = pack_bf2(st[p].z, st[p].w);
                *(int2*)(&dstA[widx[p]]) = v;
            }
        }
        __syncthreads();
    }

    // epilogue: D row in 16-tile = 4*lg + r, col = l15
    const int m0 = mi * 64 + wr * 32;
    const int nc0 = nhalf * 128 + wc * 32;
#pragma unroll
    for (int mt = 0; mt < 2; ++mt)
#pragma unroll
    for (int sub = 0; sub < 2; ++sub)
#pragma unroll
    for (int r = 0; r < 4; ++r) {
        int m = m0 + mt * 16 + lg * 4 + r;
        float v = acc[mt][sub][r] + bias[sub];
        feat[(size_t)m * 256 + nc0 + sub * 16 + l15] = fmaxf(v, 0.f);
    }
}

// ---------------------------------------------------------------------------
// Kernel 3: RoI-align (7x7 bilinear, mean) + mask + dense.  1 block per (b,n).
// FROZEN.
// ---------------------------------------------------------------------------
__global__ __launch_bounds__(512) void roi_dense_kernel(
    const float* __restrict__ bboxes,
    const float* __restrict__ feat,
    const float* __restrict__ dense_w,
    const float* __restrict__ dense_b,
    float* __restrict__ out) {
    __shared__ int   offs[4][49];
    __shared__ float wts[4][49];
    __shared__ float part[512];
    __shared__ float objv[256];

    const int bn = blockIdx.x;         // b*16 + n
    const int b  = bn >> 4;
    const int tid = threadIdx.x;

    const float4 box = *(const float4*)(bboxes + (size_t)bn * 4); // ymin,xmin,ymax,xmax
    bool empty = (box.x == -1.f) & (box.y == -1.f) & (box.z == -1.f) & (box.w == -1.f);
    if (empty) {
        if (tid < 256) out[(size_t)bn * 256 + tid] = dense_b[tid];
        return;
    }

    if (tid < 49) {
        int sy = tid / 7, sx = tid - sy * 7;
        float py = (box.x + (box.z - box.x) * ((sy + 0.5f) * (1.0f / 7.0f))) * 32.f - 0.5f;
        float px = (box.y + (box.w - box.y) * ((sx + 0.5f) * (1.0f / 7.0f))) * 32.f - 0.5f;
        float y0f = floorf(py), x0f = floorf(px);
        float wy = py - y0f, wx = px - x0f;
        int y0 = min(max((int)y0f, 0), 31);
        int y1 = min(max((int)y0f + 1, 0), 31);
        int x0 = min(max((int)x0f, 0), 31);
        int x1 = min(max((int)x0f + 1, 0), 31);
        offs[0][tid] = (y0 * 32 + x0) * 256;
        offs[1][tid] = (y0 * 32 + x1) * 256;
        offs[2][tid] = (y1 * 32 + x0) * 256;
        offs[3][tid] = (y1 * 32 + x1) * 256;
        wts[0][tid] = (1.f - wy) * (1.f - wx);
        wts[1][tid] = (1.f - wy) * wx;
        wts[2][tid] = wy * (1.f - wx);
        wts[3][tid] = wy * wx;
    }
    __syncthreads();

    const int c = tid & 255, h = tid >> 8;
    const float* fb = feat + (size_t)b * (1024 * 256) + c;
    float accv = 0.f;
    for (int s = h; s < 49; s += 2) {
        accv += wts[0][s] * fb[offs[0][s]];
        accv += wts[1][s] * fb[offs[1][s]];
        accv += wts[2][s] * fb[offs[2][s]];
        accv += wts[3][s] * fb[offs[3][s]];
    }
    part[tid] = accv;
    __syncthreads();
    if (tid < 256) objv[tid] = (part[tid] + part[tid + 256]) * (1.f / 49.f);
    __syncthreads();

    const float* dwp = dense_w + (size_t)(h * 128) * 256 + c;
    float da = 0.f;
#pragma unroll 8
    for (int cc = 0; cc < 128; ++cc) da += objv[h * 128 + cc] * dwp[(size_t)cc * 256];
    part[tid] = da;
    __syncthreads();
    if (tid < 256) out[(size_t)bn * 256 + tid] = part[tid] + part[tid + 256] + dense_b[tid];
}

extern "C" void kernel_launch(void* const* d_in, const int* in_sizes, int n_in,
                              void* d_out, int out_size, void* d_ws, size_t ws_size,
                              hipStream_t stream) {
    const float* images  = (const float*)d_in[0];   // [16,512,512,3]
    const float* bboxes  = (const float*)d_in[1];   // [16,16,4]
    const float* conv_w  = (const float*)d_in[2];   // [16,16,3,256]
    const float* conv_b  = (const float*)d_in[3];   // [256]
    const float* dense_w = (const float*)d_in[4];   // [256,256]
    const float* dense_b = (const float*)d_in[5];   // [256]
    float* out = (float*)d_out;

    char* ws = (char*)d_ws;
    i32x4* bpack = (i32x4*)ws;                      // 384 KiB (bf16 B fragments)
    float* feat  = (float*)(ws + 512 * 1024);       // 16384*256 fp32 = 16 MiB

    pack_w_kernel<<<96, 256, 0, stream>>>(conv_w, bpack);
    conv_kernel<<<512, 512, 0, stream>>>(images, bpack, conv_b, feat);
    roi_dense_kernel<<<256, 512, 0, stream>>>(bboxes, feat, dense_w, dense_b, out);
}

// Round 8
// 39.346 us; speedup vs baseline: 4.4498x; 1.0275x over previous
//
#include <hip/hip_runtime.h>
#include <hip/hip_bf16.h>

typedef __attribute__((ext_vector_type(8))) short bf16x8;
typedef __attribute__((ext_vector_type(4))) float f32x4;
typedef __attribute__((ext_vector_type(4))) int i32x4;

// RNE round two fp32 -> packed bf16 pair (elem a = low half)
__device__ inline unsigned int pack_bf2(float a, float b) {
    unsigned int ua = __builtin_bit_cast(unsigned int, a);
    unsigned int ub = __builtin_bit_cast(unsigned int, b);
    ua = (ua + 0x7fffu + ((ua >> 16) & 1u)) >> 16;
    ub = (ub + 0x7fffu + ((ub >> 16) & 1u)) >> 16;
    return (ub << 16) | (ua & 0xffffu);
}
// RNE single fp32 -> bf16 (as ushort)
__device__ inline unsigned short f2bf1(float a) {
    unsigned int u = __builtin_bit_cast(unsigned int, a);
    u = (u + 0x7fffu + ((u >> 16) & 1u)) >> 16;
    return (unsigned short)u;
}
// bf16 (ushort) -> fp32, exact
__device__ inline float bf2f(unsigned short u) {
    return __builtin_bit_cast(float, ((unsigned int)u) << 16);
}

// ---------------------------------------------------------------------------
// Kernel 1: repack conv_w [K=768][N=256] fp32 -> bf16 in MFMA B-fragment order.
// Bpack frag index t = (nt*24 + ksg)*64 + lane, 8 bf16 per t (one int4).
// B[k][n]: k = ksg*32 + (lane>>4)*8 + j, n = nt*16 + (lane&15).
// ---------------------------------------------------------------------------
__global__ void pack_w_kernel(const float* __restrict__ conv_w, i32x4* __restrict__ bpack) {
    int t = blockIdx.x * 256 + threadIdx.x;       // 0 .. 24575
    int lane = t & 63;
    int g = t >> 6;                                // nt*24 + ksg
    int nt = g / 24, ks = g - nt * 24;
    int k0 = ks * 32 + ((lane >> 4) << 3);
    int n  = nt * 16 + (lane & 15);
    const float* src = conv_w + (size_t)k0 * 256 + n;
    float v[8];
#pragma unroll
    for (int j = 0; j < 8; ++j) v[j] = src[(size_t)j * 256];
    i32x4 o;
    o.x = pack_bf2(v[0], v[1]);
    o.y = pack_bf2(v[2], v[3]);
    o.z = pack_bf2(v[4], v[5]);
    o.w = pack_bf2(v[6], v[7]);
    bpack[t] = o;
}

// ---------------------------------------------------------------------------
// Kernel 2 (R8): full-width conv stem. One block per image strip (M=32
// patches) x N=256. Images read ONCE from HBM (50.3 MB, was 100).
// K-chunk=192 (4 image rows), 4 chunks, LDS double-buffered (25.6 KB).
// Image prefetch 2 chunks deep in two STATICALLY-indexed register slots;
// per chunk, B frags (12 x i32x4, L2-resident) are issued BEFORE the image
// loads so MFMA's vmcnt wait drains only B and leaves image loads in
// flight with a full compute phase (~1900 cyc) of cover. 1 barrier/chunk.
// feat written as bf16 (8.4 MB, halves roi read as well).
// ---------------------------------------------------------------------------
__global__ __launch_bounds__(512) void conv_kernel(
    const float* __restrict__ images,
    const i32x4* __restrict__ bpack,
    const float* __restrict__ conv_b,
    unsigned short* __restrict__ featB) {
    __shared__ short ldsA[2][32 * 200];   // [buf][patch 0..31][k 0..191, stride 200]

    const int tid  = threadIdx.x;
    const int lane = tid & 63;
    const int w    = tid >> 6;        // wave 0..7 -> N columns w*32..w*32+31
    const int l15  = lane & 15;
    const int lg   = lane >> 4;       // 0..3

    const int g = blockIdx.x;         // strip 0..511
    const int b = g >> 5, ii = g & 31;

    // staging coords: row-in-chunk sr (0..3), col tc (0..127), 3 float4 each
    const int sr = tid >> 7;
    const int tc = tid & 127;
    const float* rowb = images + (size_t)(b * 512 + ii * 16 + sr) * 1536 + tc * 4;

    // LDS write indices (3 per thread)
    int widx[3];
#pragma unroll
    for (int p = 0; p < 3; ++p) {
        int f0 = tc * 4 + p * 512;            // float index within image row
        int j = f0 / 48;                      // patch column 0..31
        int off = f0 - 48 * j;                // 0..44, multiple of 4
        widx[p] = j * 200 + sr * 48 + off;
    }

    float bias[2];
#pragma unroll
    for (int sub = 0; sub < 2; ++sub)
        bias[sub] = conv_b[w * 32 + sub * 16 + l15];

    // B frags: nt = 2w + sub, index ((2w+sub)*24 + ksg)*64 + lane
    const i32x4* bp = bpack + (size_t)(2 * w * 24) * 64 + lane;

    f32x4 acc[2][2] = {};
    f32x4 ldS0[3], ldS1[3];           // 2-deep prefetch slots, statically indexed

    // ---- prologue: load+stage chunk 0, issue chunk 1 ----
    {
        f32x4 t0[3];
#pragma unroll
        for (int p = 0; p < 3; ++p) t0[p] = *(const f32x4*)(rowb + p * 512);
#pragma unroll
        for (int p = 0; p < 3; ++p) ldS1[p] = *(const f32x4*)(rowb + 4 * 1536 + p * 512);
#pragma unroll
        for (int p = 0; p < 3; ++p) {
            int2 v;
            v.x = pack_bf2(t0[p].x, t0[p].y);
            v.y = pack_bf2(t0[p].z, t0[p].w);
            *(int2*)(&ldsA[0][widx[p]]) = v;
        }
    }
    __syncthreads();

#pragma unroll
    for (int rc = 0; rc < 4; ++rc) {
        // (1) B loads for THIS chunk — L2-resident, issued before image loads
        i32x4 Bc[2][6];
#pragma unroll
        for (int sub = 0; sub < 2; ++sub)
#pragma unroll
        for (int s = 0; s < 6; ++s)
            Bc[sub][s] = bp[(size_t)(sub * 24 + rc * 6 + s) * 64];
        // (2) image loads for chunk rc+2 into the freed slot (static by unroll)
        if (rc == 0) {
#pragma unroll
            for (int p = 0; p < 3; ++p) ldS0[p] = *(const f32x4*)(rowb + 8 * 1536 + p * 512);
        }
        if (rc == 1) {
#pragma unroll
            for (int p = 0; p < 3; ++p) ldS1[p] = *(const f32x4*)(rowb + 12 * 1536 + p * 512);
        }
        // (3) compute chunk rc: 6 k-steps, waves share A rows (M=32)
        const short* bufA = &ldsA[rc & 1][0];
#pragma unroll
        for (int s = 0; s < 6; ++s) {
            bf16x8 aF0 = *(const bf16x8*)(&bufA[l15 * 200 + s * 32 + lg * 8]);
            bf16x8 aF1 = *(const bf16x8*)(&bufA[(16 + l15) * 200 + s * 32 + lg * 8]);
#pragma unroll
            for (int sub = 0; sub < 2; ++sub) {
                bf16x8 bF = __builtin_bit_cast(bf16x8, Bc[sub][s]);
                acc[0][sub] = __builtin_amdgcn_mfma_f32_16x16x32_bf16(aF0, bF, acc[0][sub], 0, 0, 0);
                acc[1][sub] = __builtin_amdgcn_mfma_f32_16x16x32_bf16(aF1, bF, acc[1][sub], 0, 0, 0);
            }
        }
        // (4) stage chunk rc+1 (its loads got a full compute phase of cover)
        if (rc < 3) {
            short* dst = &ldsA[(rc + 1) & 1][0];
            if ((rc & 1) == 0) {              // chunk rc+1 lives in ldS1
#pragma unroll
                for (int p = 0; p < 3; ++p) {
                    int2 v;
                    v.x = pack_bf2(ldS1[p].x, ldS1[p].y);
                    v.y = pack_bf2(ldS1[p].z, ldS1[p].w);
                    *(int2*)(&dst[widx[p]]) = v;
                }
            } else {                          // chunk rc+1 lives in ldS0
#pragma unroll
                for (int p = 0; p < 3; ++p) {
                    int2 v;
                    v.x = pack_bf2(ldS0[p].x, ldS0[p].y);
                    v.y = pack_bf2(ldS0[p].z, ldS0[p].w);
                    *(int2*)(&dst[widx[p]]) = v;
                }
            }
        }
        __syncthreads();
    }

    // epilogue: D row in 16-tile = 4*lg + r, col = l15; store bf16
    const int m0 = g * 32;
#pragma unroll
    for (int mt = 0; mt < 2; ++mt)
#pragma unroll
    for (int sub = 0; sub < 2; ++sub)
#pragma unroll
    for (int r = 0; r < 4; ++r) {
        int m = m0 + mt * 16 + lg * 4 + r;
        int n = w * 32 + sub * 16 + l15;
        float v = acc[mt][sub][r] + bias[sub];
        featB[(size_t)m * 256 + n] = f2bf1(fmaxf(v, 0.f));
    }
}

// ---------------------------------------------------------------------------
// Kernel 3: RoI-align (7x7 bilinear, mean) + mask + dense.  1 block per (b,n).
// feat is now bf16 (halved gather traffic); dense stays fp32.
// ---------------------------------------------------------------------------
__global__ __launch_bounds__(512) void roi_dense_kernel(
    const float* __restrict__ bboxes,
    const unsigned short* __restrict__ featB,
    const float* __restrict__ dense_w,
    const float* __restrict__ dense_b,
    float* __restrict__ out) {
    __shared__ int   offs[4][49];
    __shared__ float wts[4][49];
    __shared__ float part[512];
    __shared__ float objv[256];

    const int bn = blockIdx.x;         // b*16 + n
    const int b  = bn >> 4;
    const int tid = threadIdx.x;

    const float4 box = *(const float4*)(bboxes + (size_t)bn * 4); // ymin,xmin,ymax,xmax
    bool empty = (box.x == -1.f) & (box.y == -1.f) & (box.z == -1.f) & (box.w == -1.f);
    if (empty) {
        if (tid < 256) out[(size_t)bn * 256 + tid] = dense_b[tid];
        return;
    }

    if (tid < 49) {
        int sy = tid / 7, sx = tid - sy * 7;
        float py = (box.x + (box.z - box.x) * ((sy + 0.5f) * (1.0f / 7.0f))) * 32.f - 0.5f;
        float px = (box.y + (box.w - box.y) * ((sx + 0.5f) * (1.0f / 7.0f))) * 32.f - 0.5f;
        float y0f = floorf(py), x0f = floorf(px);
        float wy = py - y0f, wx = px - x0f;
        int y0 = min(max((int)y0f, 0), 31);
        int y1 = min(max((int)y0f + 1, 0), 31);
        int x0 = min(max((int)x0f, 0), 31);
        int x1 = min(max((int)x0f + 1, 0), 31);
        offs[0][tid] = (y0 * 32 + x0) * 256;
        offs[1][tid] = (y0 * 32 + x1) * 256;
        offs[2][tid] = (y1 * 32 + x0) * 256;
        offs[3][tid] = (y1 * 32 + x1) * 256;
        wts[0][tid] = (1.f - wy) * (1.f - wx);
        wts[1][tid] = (1.f - wy) * wx;
        wts[2][tid] = wy * (1.f - wx);
        wts[3][tid] = wy * wx;
    }
    __syncthreads();

    const int c = tid & 255, h = tid >> 8;
    const unsigned short* fb = featB + (size_t)b * (1024 * 256) + c;
    float accv = 0.f;
    for (int s = h; s < 49; s += 2) {
        accv += wts[0][s] * bf2f(fb[offs[0][s]]);
        accv += wts[1][s] * bf2f(fb[offs[1][s]]);
        accv += wts[2][s] * bf2f(fb[offs[2][s]]);
        accv += wts[3][s] * bf2f(fb[offs[3][s]]);
    }
    part[tid] = accv;
    __syncthreads();
    if (tid < 256) objv[tid] = (part[tid] + part[tid + 256]) * (1.f / 49.f);
    __syncthreads();

    const float* dwp = dense_w + (size_t)(h * 128) * 256 + c;
    float da = 0.f;
#pragma unroll 8
    for (int cc = 0; cc < 128; ++cc) da += objv[h * 128 + cc] * dwp[(size_t)cc * 256];
    part[tid] = da;
    __syncthreads();
    if (tid < 256) out[(size_t)bn * 256 + tid] = part[tid] + part[tid + 256] + dense_b[tid];
}

extern "C" void kernel_launch(void* const* d_in, const int* in_sizes, int n_in,
                              void* d_out, int out_size, void* d_ws, size_t ws_size,
                              hipStream_t stream) {
    const float* images  = (const float*)d_in[0];   // [16,512,512,3]
    const float* bboxes  = (const float*)d_in[1];   // [16,16,4]
    const float* conv_w  = (const float*)d_in[2];   // [16,16,3,256]
    const float* conv_b  = (const float*)d_in[3];   // [256]
    const float* dense_w = (const float*)d_in[4];   // [256,256]
    const float* dense_b = (const float*)d_in[5];   // [256]
    float* out = (float*)d_out;

    char* ws = (char*)d_ws;
    i32x4* bpack = (i32x4*)ws;                          // 384 KiB (bf16 B fragments)
    unsigned short* featB = (unsigned short*)(ws + 512 * 1024);  // 16384*256 bf16 = 8.4 MiB

    pack_w_kernel<<<96, 256, 0, stream>>>(conv_w, bpack);
    conv_kernel<<<512, 512, 0, stream>>>(images, bpack, conv_b, featB);
    roi_dense_kernel<<<256, 512, 0, stream>>>(bboxes, featB, dense_w, dense_b, out);
}